// Round 2
// baseline (682.402 us; speedup 1.0000x reference)
//
#include <hip/hip_runtime.h>
#include <hip/hip_bf16.h>

#define ALPHA_MARGIN 1.0f

typedef float f32x4 __attribute__((ext_vector_type(4)));

// Persistent-grid, wave-per-pair, 4-pair unroll.
// Pair row = 256 fp32 = 64 float4: lane i loads float4 #i (1 KiB/wave,
// perfectly coalesced). Lanes 0..31 hold e_a, 32..63 hold e_b;
// __shfl_xor(.,32) swaps halves, butterfly 16..1 reduces each half to the
// identical dist2. Nontemporal: X is streamed exactly once, no reuse.
__global__ __launch_bounds__(256) void closs_kernel(
        const f32x4* __restrict__ X4,
        const int*   __restrict__ y,
        float*       __restrict__ out,
        int n_pairs) {
    const int tid    = blockIdx.x * blockDim.x + threadIdx.x;
    const int wave   = tid >> 6;
    const int lane   = threadIdx.x & 63;
    const int nwaves = (gridDim.x * blockDim.x) >> 6;
    const int stride = nwaves * 4;

    for (int base = wave; base < n_pairs; base += stride) {
        // issue 4 independent 16B loads first (MLP)
        f32x4 v[4];
        #pragma unroll
        for (int k = 0; k < 4; ++k) {
            int p = base + k * nwaves;
            if (p < n_pairs)
                v[k] = __builtin_nontemporal_load(&X4[(size_t)p * 64 + lane]);
        }
        #pragma unroll
        for (int k = 0; k < 4; ++k) {
            int p = base + k * nwaves;   // wave-uniform predicate: no divergence
            if (p >= n_pairs) break;
            float dx = v[k][0] - __shfl_xor(v[k][0], 32);
            float dy = v[k][1] - __shfl_xor(v[k][1], 32);
            float dz = v[k][2] - __shfl_xor(v[k][2], 32);
            float dw = v[k][3] - __shfl_xor(v[k][3], 32);
            float s = dx * dx + dy * dy + dz * dz + dw * dw;
            #pragma unroll
            for (int m = 16; m >= 1; m >>= 1)
                s += __shfl_xor(s, m);
            if (lane == 0) {
                int adj = y[p];
                float loss = (adj == 1) ? s
                           : (adj == 0 ? fmaxf(ALPHA_MARGIN - s, 0.0f) : 0.0f);
                __builtin_nontemporal_store(loss, &out[p]);
            }
        }
    }
}

extern "C" void kernel_launch(void* const* d_in, const int* in_sizes, int n_in,
                              void* d_out, int out_size, void* d_ws, size_t ws_size,
                              hipStream_t stream) {
    const float* X = (const float*)d_in[0];
    const int*   y = (const int*)d_in[1];
    float* out = (float*)d_out;

    int n_pairs = in_sizes[1];   // B * N * N = 524288

    // persistent grid: 2048 blocks * 4 waves = 8192 waves = 32 waves/CU
    int blocks = 2048;
    closs_kernel<<<blocks, 256, 0, stream>>>((const f32x4*)X, y, out, n_pairs);
}